// Round 1
// baseline (160.321 us; speedup 1.0000x reference)
//
#include <hip/hip_runtime.h>
#include <stdint.h>

// ---------------- kernel 1: per-block min/max partials ----------------
__global__ __launch_bounds__(256) void k_minmax(const float* __restrict__ x, int n4, int ntail,
                                                float* __restrict__ partials) {
  __shared__ float smn[256], smx[256];
  int tid = threadIdx.x;
  float mn = 3.0e38f, mx = -3.0e38f;
  const float4* x4 = (const float4*)x;
  for (int i = blockIdx.x * blockDim.x + tid; i < n4; i += gridDim.x * blockDim.x) {
    float4 v = x4[i];
    mn = fminf(mn, fminf(fminf(v.x, v.y), fminf(v.z, v.w)));
    mx = fmaxf(mx, fmaxf(fmaxf(v.x, v.y), fmaxf(v.z, v.w)));
  }
  if (blockIdx.x == 0 && tid == 0) {
    for (int i = 4 * n4; i < 4 * n4 + ntail; ++i) { mn = fminf(mn, x[i]); mx = fmaxf(mx, x[i]); }
  }
  smn[tid] = mn; smx[tid] = mx;
  __syncthreads();
  for (int s = 128; s > 0; s >>= 1) {
    if (tid < s) { smn[tid] = fminf(smn[tid], smn[tid + s]); smx[tid] = fmaxf(smx[tid], smx[tid + s]); }
    __syncthreads();
  }
  if (tid == 0) { partials[2 * blockIdx.x] = smn[0]; partials[2 * blockIdx.x + 1] = smx[0]; }
}

// ---------------- kernel 2: finalize min/max, build byte table, copy small outs ----------------
// ws layout (dwords): [0]=mn [1]=mx [2..17]=byte table (8 rows x 2 dwords)
//                     [18..25]=row scale  [26..33]=row offset(cmin)  [64..]=partials
__global__ __launch_bounds__(256) void k_params(const float* __restrict__ partials, int nb,
                                                const float* __restrict__ co, const float* __restrict__ sfil,
                                                float* __restrict__ ws,
                                                float* __restrict__ out_co, float* __restrict__ out_sf) {
  __shared__ float smn[256], smx[256];
  int tid = threadIdx.x;
  float mn = 3.0e38f, mx = -3.0e38f;
  for (int i = tid; i < nb; i += 256) { mn = fminf(mn, partials[2 * i]); mx = fmaxf(mx, partials[2 * i + 1]); }
  smn[tid] = mn; smx[tid] = mx;
  __syncthreads();
  for (int s = 128; s > 0; s >>= 1) {
    if (tid < s) { smn[tid] = fminf(smn[tid], smn[tid + s]); smx[tid] = fmaxf(smx[tid], smx[tid + s]); }
    __syncthreads();
  }
  if (tid == 0) { ws[0] = smn[0]; ws[1] = smx[0]; }
  if (tid < 8) {
    const float* r = co + tid * 8;
    float rmn = r[0], rmx = r[0];
    #pragma unroll
    for (int j = 1; j < 8; ++j) { rmn = fminf(rmn, r[j]); rmx = fmaxf(rmx, r[j]); }
    float rs = (rmx - rmn) * (1.0f / 255.0f);
    if (rs < 1e-30f) rs = 1.0f;
    uint32_t d0 = 0, d1 = 0;
    #pragma unroll
    for (int j = 0; j < 8; ++j) {
      int b = (int)lrintf((r[j] - rmn) / rs);
      b = b < 0 ? 0 : (b > 255 ? 255 : b);
      if (j < 4) d0 |= ((uint32_t)b) << (8 * j);
      else       d1 |= ((uint32_t)b) << (8 * (j - 4));
    }
    uint32_t* wsu = (uint32_t*)ws;
    wsu[2 + 2 * tid] = d0;
    wsu[3 + 2 * tid] = d1;
    ws[18 + tid] = rs;
    ws[26 + tid] = rmn;
  }
  if (tid < 64) out_co[tid] = co[tid];
  if (tid < 27) out_sf[tid] = sfil[tid];
}

// ---------------- kernel 3: fused quantize + selected 27-tap stencil ----------------
// tile: 4 c-planes x 8 h-rows x 128 w per block; 256 threads = 32(w) x 8(h); 4 w-outputs/thread
#define LROW 132
#define LPLANE (10 * LROW)
#define LTOT (6 * LPLANE)

__global__ __launch_bounds__(256) void k_conv(const float* __restrict__ x, const float* __restrict__ sfil,
                                              const float* __restrict__ ws,
                                              float* __restrict__ out, float* __restrict__ out_idx) {
  __shared__ __align__(16) uint32_t ldsx[LTOT];
  __shared__ __align__(16) uint32_t tblB[16];
  __shared__ float tblS[8];
  __shared__ float tblC[8];
  int tid = threadIdx.x;
  int b = blockIdx.x;
  int wt = b & 1, ht = (b >> 1) & 31, ct = (b >> 6) & 3, n = b >> 8;
  int c0 = ct * 4, h0 = ht * 8, w0 = wt * 128;

  float mn = ws[0], mx = ws[1];
  const uint32_t* wsu = (const uint32_t*)ws;
  if (tid < 16) tblB[tid] = wsu[2 + tid];
  else if (tid < 24) tblS[tid - 16] = ws[18 + (tid - 16)];
  else if (tid < 32) tblC[tid - 24] = ws[26 + (tid - 24)];

  int nbase = n * 16;
  // stage packed (x_bits & ~15) | q into LDS, zero outside bounds (zero padding)
  for (int e = tid; e < 7800; e += 256) {
    int lc = e / 1300;
    int r  = e - lc * 1300;
    int lh = r / 130;
    int lw = r - lh * 130;
    int c = c0 - 1 + lc, h = h0 - 1 + lh, w = w0 - 1 + lw;
    uint32_t pk = 0u;
    if (((unsigned)c < 16u) & ((unsigned)h < 256u) & ((unsigned)w < 256u)) {
      float xv = x[((nbase + c) << 16) + (h << 8) + w];
      float t = (xv - mn) / mx * 8.0f;   // must match reference rounding: sub, div, mul-by-8
      int q = (int)floorf(t);            // q in [0,8] (8 only when ratio rounds to 1.0)
      pk = (__float_as_uint(xv) & 0xFFFFFFF0u) | (uint32_t)q;
    }
    ldsx[(lc * 10 + lh) * LROW + lw] = pk;
  }
  __syncthreads();

  float wf[27];
  #pragma unroll
  for (int i = 0; i < 27; ++i) wf[i] = sfil[i];   // uniform -> scalar loads

  int tw = tid & 31, th = tid >> 5;

  for (int c = 0; c < 4; ++c) {
    // centers: lc = c+1, lh = th+1, lw = 4tw+1+k  -> m = k+1 of the 6-value row
    const uint32_t* Lc = &ldsx[((c + 1) * 10 + (th + 1)) * LROW + 4 * tw];
    uint4 A0 = *(const uint4*)Lc;
    uint2 B0 = *(const uint2*)(Lc + 4);
    uint32_t q0[4] = { A0.y & 15u, A0.z & 15u, A0.w & 15u, B0.x & 15u };
    uint32_t rlo[4], rhi[4];
    float rsv[4], rcv[4];
    #pragma unroll
    for (int k = 0; k < 4; ++k) {
      uint32_t qc = q0[k] > 7u ? 7u : q0[k];
      uint2 row = *(const uint2*)&tblB[qc * 2];
      rlo[k] = row.x; rhi[k] = row.y;
      rsv[k] = tblS[qc]; rcv[k] = tblC[qc];
    }
    float acc1[4] = {0.f, 0.f, 0.f, 0.f};
    float acc2[4] = {0.f, 0.f, 0.f, 0.f};
    #pragma unroll
    for (int dc = 0; dc < 3; ++dc) {
      #pragma unroll
      for (int di = 0; di < 3; ++di) {
        const uint32_t* L = &ldsx[((c + dc) * 10 + (th + di)) * LROW + 4 * tw];
        uint4 A = *(const uint4*)L;       // ds_read_b128, conflict-free (contiguous per half-wave)
        uint2 B = *(const uint2*)(L + 4); // ds_read_b64
        uint32_t p[6] = { A.x, A.y, A.z, A.w, B.x, B.y };
        float xv[6]; uint32_t sel[6];
        #pragma unroll
        for (int m = 0; m < 6; ++m) {
          uint32_t qm = p[m] & 15u;
          qm = qm > 7u ? 7u : qm;          // JAX gather clamps OOB index
          sel[m] = qm | 0x0c0c0c00u;       // v_perm: byte0 = table byte qm, bytes1-3 = 0x00
          xv[m] = __uint_as_float(p[m] & 0xFFFFFFF0u);
        }
        #pragma unroll
        for (int dj = 0; dj < 3; ++dj) {
          float wv = wf[dc * 9 + di * 3 + dj];
          #pragma unroll
          for (int k = 0; k < 4; ++k) {
            int m = k + dj;
            float t = wv * xv[m];
            acc2[k] += t;
            uint32_t bb = __builtin_amdgcn_perm(rhi[k], rlo[k], sel[m]);
            acc1[k] = fmaf(t, (float)bb, acc1[k]);
          }
        }
      }
    }
    int gbase = ((nbase + c0 + c) << 16) + ((h0 + th) << 8) + (w0 + 4 * tw);
    float4 o;
    float vals[4];
    #pragma unroll
    for (int k = 0; k < 4; ++k) {
      float v = fmaf(rsv[k], acc1[k], rcv[k] * acc2[k]);
      vals[k] = (q0[k] > 7u) ? 0.0f : v;   // idx==8 matches no mask channel -> 0
    }
    o.x = vals[0]; o.y = vals[1]; o.z = vals[2]; o.w = vals[3];
    *(float4*)&out[gbase] = o;
    // idx chunk starts at +91 floats -> misaligned for float4; scalar stores
    out_idx[gbase + 0] = (float)q0[0];
    out_idx[gbase + 1] = (float)q0[1];
    out_idx[gbase + 2] = (float)q0[2];
    out_idx[gbase + 3] = (float)q0[3];
  }
}

extern "C" void kernel_launch(void* const* d_in, const int* in_sizes, int n_in,
                              void* d_out, int out_size, void* d_ws, size_t ws_size,
                              hipStream_t stream) {
  const float* x    = (const float*)d_in[0];
  const float* co   = (const float*)d_in[1];
  const float* sfil = (const float*)d_in[2];
  float* out = (float*)d_out;
  float* ws  = (float*)d_ws;
  int nx = in_sizes[0];  // 8*16*256*256

  int nb1 = 512;
  size_t need = (64 + 2 * (size_t)nb1) * 4;
  if (ws_size < need) {
    long avail = (long)(ws_size / 4) - 64;
    long nb = avail > 2 ? avail / 2 : 1;
    nb1 = (int)(nb < 1 ? 1 : (nb > 512 ? 512 : nb));
  }
  float* partials = ws + 64;
  int n4 = nx / 4, ntail = nx - 4 * n4;

  float* out_co  = out + nx;
  float* out_sf  = out + nx + 64;
  float* out_idx = out + nx + 64 + 27;

  k_minmax<<<nb1, 256, 0, stream>>>(x, n4, ntail, partials);
  k_params<<<1, 256, 0, stream>>>(partials, nb1, co, sfil, ws, out_co, out_sf);
  k_conv<<<2048, 256, 0, stream>>>(x, sfil, ws, out, out_idx);
}

// Round 2
// 139.903 us; speedup vs baseline: 1.1459x; 1.1459x over previous
//
#include <hip/hip_runtime.h>
#include <stdint.h>

#define LISTBASE 4096   // dword offset of fixup list in ws
#define QCAP     4096   // max fixup entries

// ---------------- kernel 1: per-block min/max partials ----------------
__global__ __launch_bounds__(256) void k_minmax(const float* __restrict__ x, int n4, int ntail,
                                                float* __restrict__ partials) {
  __shared__ float smn[256], smx[256];
  int tid = threadIdx.x;
  float mn = 3.0e38f, mx = -3.0e38f;
  const float4* x4 = (const float4*)x;
  for (int i = blockIdx.x * blockDim.x + tid; i < n4; i += gridDim.x * blockDim.x) {
    float4 v = x4[i];
    mn = fminf(mn, fminf(fminf(v.x, v.y), fminf(v.z, v.w)));
    mx = fmaxf(mx, fmaxf(fmaxf(v.x, v.y), fmaxf(v.z, v.w)));
  }
  if (blockIdx.x == 0 && tid == 0) {
    for (int i = 4 * n4; i < 4 * n4 + ntail; ++i) { mn = fminf(mn, x[i]); mx = fmaxf(mx, x[i]); }
  }
  smn[tid] = mn; smx[tid] = mx;
  __syncthreads();
  for (int s = 128; s > 0; s >>= 1) {
    if (tid < s) { smn[tid] = fminf(smn[tid], smn[tid + s]); smx[tid] = fmaxf(smx[tid], smx[tid + s]); }
    __syncthreads();
  }
  if (tid == 0) { partials[2 * blockIdx.x] = smn[0]; partials[2 * blockIdx.x + 1] = smx[0]; }
}

// ---------------- kernel 2: finalize min/max, recip, byte table, copy small outs ----------------
// ws dwords: [0]=mn [1]=mx [2]=y=1/mx [3]=fixup counter
//            [8..39]=table: 8 entries x (rlo,rhi,scale,offset)
//            [64..]=partials   [4096..]=fixup list
__global__ __launch_bounds__(256) void k_params(const float* __restrict__ partials, int nb,
                                                const float* __restrict__ co, const float* __restrict__ sfil,
                                                float* __restrict__ ws,
                                                float* __restrict__ out_co, float* __restrict__ out_sf) {
  __shared__ float smn[256], smx[256];
  int tid = threadIdx.x;
  float mn = 3.0e38f, mx = -3.0e38f;
  for (int i = tid; i < nb; i += 256) { mn = fminf(mn, partials[2 * i]); mx = fmaxf(mx, partials[2 * i + 1]); }
  smn[tid] = mn; smx[tid] = mx;
  __syncthreads();
  for (int s = 128; s > 0; s >>= 1) {
    if (tid < s) { smn[tid] = fminf(smn[tid], smn[tid + s]); smx[tid] = fmaxf(smx[tid], smx[tid + s]); }
    __syncthreads();
  }
  if (tid == 0) {
    ws[0] = smn[0]; ws[1] = smx[0];
    ws[2] = 1.0f / smx[0];            // correctly-rounded reciprocal (full IEEE div here, once)
    ((uint32_t*)ws)[3] = 0u;          // fixup counter
  }
  if (tid < 8) {
    const float* r = co + tid * 8;
    float rmn = r[0], rmx = r[0];
    #pragma unroll
    for (int j = 1; j < 8; ++j) { rmn = fminf(rmn, r[j]); rmx = fmaxf(rmx, r[j]); }
    float rs = (rmx - rmn) * (1.0f / 255.0f);
    if (rs < 1e-30f) rs = 1.0f;
    uint32_t d0 = 0, d1 = 0;
    #pragma unroll
    for (int j = 0; j < 8; ++j) {
      int b = (int)lrintf((r[j] - rmn) / rs);
      b = b < 0 ? 0 : (b > 255 ? 255 : b);
      if (j < 4) d0 |= ((uint32_t)b) << (8 * j);
      else       d1 |= ((uint32_t)b) << (8 * (j - 4));
    }
    uint32_t* wsu = (uint32_t*)ws;
    wsu[8 + 4 * tid + 0] = d0;
    wsu[8 + 4 * tid + 1] = d1;
    wsu[8 + 4 * tid + 2] = __float_as_uint(rs);
    wsu[8 + 4 * tid + 3] = __float_as_uint(rmn);
  }
  if (tid < 64) out_co[tid] = co[tid];
  if (tid < 27) out_sf[tid] = sfil[tid];
}

// ---------------- kernel 3: fused quantize + selected 27-tap stencil ----------------
// tile: 4 c x 8 h x 128 w; 256 threads = 32(w) x 8(h); 4 w-outputs/thread
__global__ __launch_bounds__(256) void k_conv(const float* __restrict__ x, const float* __restrict__ sfil,
                                              float* __restrict__ ws, int listcap,
                                              float* __restrict__ out, float* __restrict__ out_idx) {
  __shared__ __align__(16) float    xs[7920];    // 6 planes x 10 rows x 132
  __shared__ __align__(16) uint32_t qls[1980];   // 6 x 10 x 33 (4 clamped q-bytes per dword)
  __shared__ __align__(16) uint4    tbl[8];      // rlo, rhi, scale, offset per q0

  int tid = threadIdx.x;
  int b = blockIdx.x;
  int wt = b & 1, ht = (b >> 1) & 31, ct = (b >> 6) & 3, n = b >> 8;
  int c0 = ct * 4, h0 = ht * 8, w0 = wt * 128;
  int nbase = n * 16;

  const uint32_t* wsu = (const uint32_t*)ws;
  if (tid < 8) tbl[tid] = ((const uint4*)(wsu + 8))[tid];

  float mn = ws[0], mx = ws[1], y = ws[2];
  uint32_t* cnt = (uint32_t*)ws + 3;
  int* list = (int*)ws + LISTBASE;

  // ---- staging: 1980 float4-groups of (clean x, clamped q byte) ----
  for (int e = tid; e < 1980; e += 256) {
    int lc = e / 330;
    int r  = e - lc * 330;
    int lh = r / 33;
    int lg = r - lh * 33;
    int c = c0 - 1 + lc, h = h0 - 1 + lh, wb = w0 - 1 + 4 * lg;
    bool chok = ((unsigned)c < 16u) & ((unsigned)h < 256u);
    int gofs = ((nbase + c) << 16) + (h << 8) + wb;
    float xv[4]; int qi[4]; uint32_t qu[4];
    #pragma unroll
    for (int j = 0; j < 4; ++j) {
      float xj = 0.0f;
      if (chok & ((unsigned)(wb + j) < 256u)) xj = x[gofs + j];
      // bit-exact d = fl((x-mn)/mx) via Markstein (y correctly rounded, 2 corrections)
      float s  = xj - mn;
      float t0 = s * y;
      float r0 = __builtin_fmaf(-mx, t0, s);
      float t1 = __builtin_fmaf(r0, y, t0);
      float r1 = __builtin_fmaf(-mx, t1, s);
      float d  = __builtin_fmaf(r1, y, t1);
      int q = (int)(d * 8.0f);          // trunc == floor (d >= -tiny -> 0)
      xv[j] = xj; qi[j] = q;
      qu[j] = (uint32_t)(q > 7 ? 7 : q);
    }
    if (((qi[0] | qi[1] | qi[2] | qi[3]) & 8) != 0) {   // rare: idx==8 (x at global max)
      #pragma unroll
      for (int j = 0; j < 4; ++j) if (qi[j] == 8) {
        uint32_t slot = atomicAdd(cnt, 1u);
        if (slot < (uint32_t)listcap) list[slot] = gofs + j;
      }
    }
    uint32_t b01 = __builtin_amdgcn_perm(qu[1], qu[0], 0x0c0c0400u);  // q0 | q1<<8
    uint32_t b23 = __builtin_amdgcn_perm(qu[3], qu[2], 0x04000c0cu);  // q2<<16 | q3<<24
    int ro = lc * 10 + lh;
    *(float4*)&xs[ro * 132 + 4 * lg] = float4{xv[0], xv[1], xv[2], xv[3]};
    qls[ro * 33 + lg] = b01 | b23;
  }
  __syncthreads();

  float wf[27];
  #pragma unroll
  for (int i = 0; i < 27; ++i) wf[i] = sfil[i];   // uniform -> scalar regs

  const int tw = tid & 31, th = tid >> 5;
  const uint32_t SELK[4] = {0x03020100u, 0x04030201u, 0x05040302u, 0x06050403u};

  for (int c = 0; c < 4; ++c) {
    int xbase = (c * 10 + th) * 132 + 4 * tw;
    int qbase = (c * 10 + th) * 33 + tw;

    // center q-bytes (window m=1..4) + per-output table rows
    int qc = qbase + 11 * 33;
    uint32_t Qc0 = qls[qc], Qc1 = qls[qc + 1];
    uint32_t q4 = __builtin_amdgcn_perm(Qc1, Qc0, 0x04030201u);
    uint32_t rlo[4], rhi[4]; float rs4[4], rc4[4];
    #pragma unroll
    for (int k = 0; k < 4; ++k) {
      uint32_t qk = (q4 >> (8 * k)) & 0xffu;
      uint4 T = tbl[qk];                  // conflict-free broadcast b128
      rlo[k] = T.x; rhi[k] = T.y;
      rs4[k] = __uint_as_float(T.z); rc4[k] = __uint_as_float(T.w);
    }

    float acc1[4] = {0.f, 0.f, 0.f, 0.f};
    float acc2[4] = {0.f, 0.f, 0.f, 0.f};
    #pragma unroll
    for (int dc = 0; dc < 3; ++dc) {
      #pragma unroll
      for (int di = 0; di < 3; ++di) {
        int xo = xbase + (dc * 10 + di) * 132;
        float4 A = *(const float4*)&xs[xo];
        float2 B = *(const float2*)&xs[xo + 4];
        int qo = qbase + (dc * 10 + di) * 33;
        uint32_t Q0 = qls[qo], Q1 = qls[qo + 1];
        float xw[6] = {A.x, A.y, A.z, A.w, B.x, B.y};
        const float* wr = &wf[dc * 9 + di * 3];
        #pragma unroll
        for (int k = 0; k < 4; ++k) {
          uint32_t sel = __builtin_amdgcn_perm(Q1, Q0, SELK[k]);   // 3 q-bytes for taps
          uint32_t bb  = __builtin_amdgcn_perm(rhi[k], rlo[k], sel); // 3 table bytes
          float b0 = (float)(bb & 0xffu);          // v_cvt_f32_ubyte0
          float b1 = (float)((bb >> 8) & 0xffu);   // v_cvt_f32_ubyte1
          float b2 = (float)((bb >> 16) & 0xffu);  // v_cvt_f32_ubyte2
          float p0 = wr[0] * xw[k];
          float p1 = wr[1] * xw[k + 1];
          float p2 = wr[2] * xw[k + 2];
          acc2[k] += p0 + p1 + p2;
          acc1[k] = __builtin_fmaf(p0, b0, acc1[k]);
          acc1[k] = __builtin_fmaf(p1, b1, acc1[k]);
          acc1[k] = __builtin_fmaf(p2, b2, acc1[k]);
        }
      }
    }
    int gbase = ((nbase + c0 + c) << 16) + ((h0 + th) << 8) + (w0 + 4 * tw);
    float4 o;
    o.x = __builtin_fmaf(rs4[0], acc1[0], rc4[0] * acc2[0]);
    o.y = __builtin_fmaf(rs4[1], acc1[1], rc4[1] * acc2[1]);
    o.z = __builtin_fmaf(rs4[2], acc1[2], rc4[2] * acc2[2]);
    o.w = __builtin_fmaf(rs4[3], acc1[3], rc4[3] * acc2[3]);
    *(float4*)&out[gbase] = o;
    out_idx[gbase + 0] = (float)(q4 & 0xffu);
    out_idx[gbase + 1] = (float)((q4 >> 8) & 0xffu);
    out_idx[gbase + 2] = (float)((q4 >> 16) & 0xffu);
    out_idx[gbase + 3] = (float)((q4 >> 24) & 0xffu);
  }
}

// ---------------- kernel 4: rare idx==8 fixup ----------------
__global__ __launch_bounds__(256) void k_fix(const float* __restrict__ ws, int listcap,
                                             float* __restrict__ out, float* __restrict__ out_idx) {
  uint32_t n = ((const uint32_t*)ws)[3];
  if (n > (uint32_t)listcap) n = (uint32_t)listcap;
  const int* list = (const int*)ws + LISTBASE;
  for (uint32_t i = threadIdx.x; i < n; i += 256) {
    int p = list[i];
    out[p] = 0.0f;      // idx==8 matches no mask channel
    out_idx[p] = 8.0f;  // true (unclamped) idx
  }
}

extern "C" void kernel_launch(void* const* d_in, const int* in_sizes, int n_in,
                              void* d_out, int out_size, void* d_ws, size_t ws_size,
                              hipStream_t stream) {
  const float* x    = (const float*)d_in[0];
  const float* co   = (const float*)d_in[1];
  const float* sfil = (const float*)d_in[2];
  float* out = (float*)d_out;
  float* ws  = (float*)d_ws;
  int nx = in_sizes[0];  // 8*16*256*256

  int nb1 = 1024;
  long wsd = (long)(ws_size / 4);
  long maxnb = (wsd - 64) / 2;
  if (maxnb > 2016) maxnb = 2016;         // partials must end before list base
  if (nb1 > maxnb) nb1 = (int)(maxnb < 1 ? 1 : maxnb);
  int listcap = (int)(wsd - LISTBASE);
  if (listcap > QCAP) listcap = QCAP;
  if (listcap < 0) listcap = 0;

  float* partials = ws + 64;
  int n4 = nx / 4, ntail = nx - 4 * n4;

  float* out_co  = out + nx;
  float* out_sf  = out + nx + 64;
  float* out_idx = out + nx + 64 + 27;

  k_minmax<<<nb1, 256, 0, stream>>>(x, n4, ntail, partials);
  k_params<<<1, 256, 0, stream>>>(partials, nb1, co, sfil, ws, out_co, out_sf);
  k_conv<<<2048, 256, 0, stream>>>(x, sfil, ws, listcap, out, out_idx);
  k_fix<<<1, 256, 0, stream>>>(ws, listcap, out, out_idx);
}